// Round 8
// baseline (135.406 us; speedup 1.0000x reference)
//
#include <hip/hip_runtime.h>

#define WW 512
#define HH 256
#define TS 48
#define NB 2
#define ZB 4                 // z-rows per block
#define NZB (HH / ZB)        // 64
#define TCH 12               // t-steps per block
#define NCH (TS / TCH)       // 4
#define KAPPA 0.01f
#define NU 0.01f
#define LDSW 512
#define NROWS 30             // 24 T/U/V stencil rows + 6 pre-summed P rows

#define LD4(p) (*reinterpret_cast<const float4*>(p))
#define CLZ(v) (min(max((v), 0), HH - 1))

__device__ __forceinline__ float elem(const float4 v, int e) {
    return e == 0 ? v.x : e == 1 ? v.y : e == 2 ? v.z : v.w;
}
__device__ __forceinline__ float4 f4add(const float4 a, const float4 b) {
    return make_float4(a.x + b.x, a.y + b.y, a.z + b.z, a.w + b.w);
}

// jnp.gradient first+second (gradient-of-gradient) along one axis, index i of n.
__device__ __forceinline__ void grad12(float fm2, float fm1, float fc, float fp1, float fp2,
                                       int i, int n, float invh, float& g, float& gg) {
    const float half = 0.5f * invh;
    if (i == 0) {
        g = (fp1 - fc) * invh;
        float g1 = (fp2 - fc) * half;
        gg = (g1 - g) * invh;
    } else if (i == n - 1) {
        g = (fc - fm1) * invh;
        float gm = (fc - fm2) * half;
        gg = (g - gm) * invh;
    } else {
        g = (fp1 - fm1) * half;
        float gim = (i == 1)     ? (fc - fm1) * invh : (fc - fm2) * half;
        float gip = (i == n - 2) ? (fp1 - fc) * invh : (fp2 - fc) * half;
        gg = (gip - gim) * half;
    }
}

__device__ __forceinline__ float grad1(float fm1, float fc, float fp1, int i, int n, float invh) {
    if (i == 0)     return (fp1 - fc) * invh;
    if (i == n - 1) return (fc - fm1) * invh;
    return (fp1 - fm1) * (0.5f * invh);
}

__global__ __launch_bounds__(512, 4) void rbc_loss_kernel(const float* __restrict__ pred,
                                                          double* __restrict__ dacc) {
    const int sT = HH * WW;          // 131072
    const int sC = TS * sT;
    const int sB = 5 * sC;

    __shared__ __align__(16) float lds[NROWS * LDSW];   // 60 KB

    // XCD-chunked swizzle: 512 blocks, 64/XCD -> each XCD owns one (b,tc) full-z sweep.
    const int bi = blockIdx.x;
    const int n  = (bi & 7) * (gridDim.x >> 3) + (bi >> 3);

    const int zb = n & (NZB - 1);         // n = ((b*NCH + tc)*NZB + zb)
    const int tc = (n >> 6) & (NCH - 1);
    const int b  = n >> 8;
    const int t0 = tc * TCH;
    const int z0 = zb * ZB;

    const int lane = threadIdx.x & 63;
    const int w = threadIdx.x >> 6;       // 0..7
    const int r  = w >> 1;                // z-row within block, 0..3
    const int xh = w & 1;                 // x-half
    const int z  = z0 + r;
    const int x0 = (xh << 8) + (lane << 2);
    const int cr = r + 2;                 // center's row index within T/U/V stage
    const int qc = r + 1;                 // center's row index within P stage

    const float invdt = TS / 10.0f;
    const float invdx = (float)(WW / 6.283185307179586);
    const float invdz = HH / 2.0f;

    const float* __restrict__ pT = pred + (size_t)b * sB;
    const float* __restrict__ pU = pT + (size_t)sC;
    const float* __restrict__ pV = pT + 2 * (size_t)sC;
    const float* __restrict__ q3 = pT + 3 * (size_t)sC;
    // q4 = q3 + sC

    // ---- stage assignment: 60 half-row copies, c = w + 8k ----
    const float* sb[8]; int lo[8];
    #pragma unroll
    for (int k = 0; k < 8; ++k) {
        const int c = w + 8 * k;
        sb[k] = nullptr; lo[k] = 0;
        if (c < 60) {
            const int h = c & 1;
            int ldsrow, zr; const float* base;
            if (c < 48) {                     // T/U/V rows z0-2 .. z0+5
                const int j = c >> 1;
                base = (j < 8) ? pT : (j < 16) ? pU : pV;
                zr = CLZ(z0 - 2 + (j & 7));
                ldsrow = j;
            } else {                          // P rows z0-1 .. z0+4 (q3+q4 summed)
                const int pr = (c - 48) >> 1;
                base = q3;
                zr = CLZ(z0 - 1 + pr);
                ldsrow = 24 + pr;
            }
            sb[k] = base + zr * WW + h * 256 + lane * 4;
            lo[k] = ldsrow * LDSW + h * 256 + (lane << 2);
        }
    }

    // ---- t-ring warmup: centers at t0-1 (clamped) and t0 ----
    const int rCg = z * WW + x0;
    const int tp0 = max(t0 - 1, 0);
    float4 Tp = LD4(pT + (size_t)tp0 * sT + rCg);
    float4 Up = LD4(pU + (size_t)tp0 * sT + rCg);
    float4 Vp = LD4(pV + (size_t)tp0 * sT + rCg);
    float4 Tc = LD4(pT + (size_t)t0 * sT + rCg);
    float4 Uc = LD4(pU + (size_t)t0 * sT + rCg);
    float4 Vc = LD4(pV + (size_t)t0 * sT + rCg);

    const bool isR = (lane == 63) && (xh == 0);   // needs x=256,257 from LDS
    const bool isL = (lane == 0)  && (xh == 1);   // needs x=254,255 from LDS

    float acc = 0.f;

    #pragma unroll 1
    for (int t = t0; t < t0 + TCH; ++t) {
        const size_t o  = (size_t)t * sT;
        const size_t on = (size_t)min(t + 1, TS - 1) * sT;

        // coldest first: t+1 centers (kept in regs through compute)
        float4 Tn = LD4(pT + on + rCg);
        float4 Un = LD4(pU + on + rCg);
        float4 Vn = LD4(pV + on + rCg);

        // cooperative stage: burst loads, then LDS writes
        float4 sv[8];
        #pragma unroll
        for (int k = 0; k < 8; ++k) {
            const int c = w + 8 * k;
            if (c < 60) {
                sv[k] = LD4(sb[k] + o);
                if (c >= 48) sv[k] = f4add(sv[k], LD4(sb[k] + o + (size_t)sC));
            }
        }
        #pragma unroll
        for (int k = 0; k < 8; ++k) {
            const int c = w + 8 * k;
            if (c < 60) *reinterpret_cast<float4*>(&lds[lo[k]]) = sv[k];
        }
        __syncthreads();

        // ================= compute (from LDS + ring regs) =================
        // ---- P ----
        const int Pb = 24 + qc;
        float4 Pm1 = LD4(&lds[(Pb - 1) * LDSW + x0]);
        float4 Pc  = LD4(&lds[(Pb    ) * LDSW + x0]);
        float4 Pp1 = LD4(&lds[(Pb + 1) * LDSW + x0]);
        float Pl3 = __shfl_up(Pc.w, 1), Pr0 = __shfl_down(Pc.x, 1);
        if (isR) Pr0 = lds[Pb * LDSW + 256];
        if (isL) Pl3 = lds[Pb * LDSW + 255];
        float dPdx[4], dPdz[4];
        #pragma unroll
        for (int e = 0; e < 4; ++e) {
            const float pxm1 = e == 0 ? Pl3 : elem(Pc, e - 1);
            const float pxc  = elem(Pc, e);
            const float pxp1 = e == 3 ? Pr0 : elem(Pc, e + 1);
            dPdx[e] = grad1(pxm1, pxc, pxp1, x0 + e, WW, invdx);
            dPdz[e] = grad1(elem(Pm1, e), pxc, elem(Pp1, e), z, HH, invdz);
        }

        // ---- T (finishes te immediately) ----
        float4 Zm2 = LD4(&lds[(cr - 2) * LDSW + x0]);
        float4 Zm1 = LD4(&lds[(cr - 1) * LDSW + x0]);
        float4 Zp1 = LD4(&lds[(cr + 1) * LDSW + x0]);
        float4 Zp2 = LD4(&lds[(cr + 2) * LDSW + x0]);
        float L2v = __shfl_up(Tc.z, 1),   L3v = __shfl_up(Tc.w, 1);
        float R0v = __shfl_down(Tc.x, 1), R1v = __shfl_down(Tc.y, 1);
        if (isR) { float2 s = *(const float2*)&lds[cr * LDSW + 256]; R0v = s.x; R1v = s.y; }
        if (isL) { float2 s = *(const float2*)&lds[cr * LDSW + 254]; L2v = s.x; L3v = s.y; }
        #pragma unroll
        for (int e = 0; e < 4; ++e) {
            const float fm2 = e == 0 ? L2v : e == 1 ? L3v : elem(Tc, e - 2);
            const float fm1 = e == 0 ? L3v : elem(Tc, e - 1);
            const float fc  = elem(Tc, e);
            const float fp1 = e == 3 ? R0v : elem(Tc, e + 1);
            const float fp2 = e == 2 ? R0v : e == 3 ? R1v : elem(Tc, e + 2);
            float gx, gxx, gz, gzz;
            grad12(fm2, fm1, fc, fp1, fp2, x0 + e, WW, invdx, gx, gxx);
            grad12(elem(Zm2, e), elem(Zm1, e), fc, elem(Zp1, e), elem(Zp2, e), z, HH, invdz, gz, gzz);
            float gt;
            if (t == 0)            gt = (elem(Tn, e) - fc) * invdt;
            else if (t == TS - 1)  gt = (fc - elem(Tp, e)) * invdt;
            else                   gt = (elem(Tn, e) - elem(Tp, e)) * (0.5f * invdt);
            const float uxc = elem(Uc, e), vxc = elem(Vc, e);
            float te = gt + uxc * gx + vxc * gz - KAPPA * (gxx + gzz);
            acc += te * te;
        }

        // ---- U (finishes xm; saves dUdx for div) ----
        Zm2 = LD4(&lds[(8 + cr - 2) * LDSW + x0]);
        Zm1 = LD4(&lds[(8 + cr - 1) * LDSW + x0]);
        Zp1 = LD4(&lds[(8 + cr + 1) * LDSW + x0]);
        Zp2 = LD4(&lds[(8 + cr + 2) * LDSW + x0]);
        L2v = __shfl_up(Uc.z, 1);   L3v = __shfl_up(Uc.w, 1);
        R0v = __shfl_down(Uc.x, 1); R1v = __shfl_down(Uc.y, 1);
        if (isR) { float2 s = *(const float2*)&lds[(8 + cr) * LDSW + 256]; R0v = s.x; R1v = s.y; }
        if (isL) { float2 s = *(const float2*)&lds[(8 + cr) * LDSW + 254]; L2v = s.x; L3v = s.y; }
        float dUdxS[4];
        #pragma unroll
        for (int e = 0; e < 4; ++e) {
            const float fm2 = e == 0 ? L2v : e == 1 ? L3v : elem(Uc, e - 2);
            const float fm1 = e == 0 ? L3v : elem(Uc, e - 1);
            const float fc  = elem(Uc, e);
            const float fp1 = e == 3 ? R0v : elem(Uc, e + 1);
            const float fp2 = e == 2 ? R0v : e == 3 ? R1v : elem(Uc, e + 2);
            float gx, gxx, gz, gzz;
            grad12(fm2, fm1, fc, fp1, fp2, x0 + e, WW, invdx, gx, gxx);
            grad12(elem(Zm2, e), elem(Zm1, e), fc, elem(Zp1, e), elem(Zp2, e), z, HH, invdz, gz, gzz);
            float gt;
            if (t == 0)            gt = (elem(Un, e) - fc) * invdt;
            else if (t == TS - 1)  gt = (fc - elem(Up, e)) * invdt;
            else                   gt = (elem(Un, e) - elem(Up, e)) * (0.5f * invdt);
            const float vxc = elem(Vc, e);
            float xm = gt + fc * gx + vxc * gz + dPdx[e] - NU * (gxx + gzz);
            acc += xm * xm;
            dUdxS[e] = gx;
        }

        // ---- V (finishes zm and div) ----
        Zm2 = LD4(&lds[(16 + cr - 2) * LDSW + x0]);
        Zm1 = LD4(&lds[(16 + cr - 1) * LDSW + x0]);
        Zp1 = LD4(&lds[(16 + cr + 1) * LDSW + x0]);
        Zp2 = LD4(&lds[(16 + cr + 2) * LDSW + x0]);
        L2v = __shfl_up(Vc.z, 1);   L3v = __shfl_up(Vc.w, 1);
        R0v = __shfl_down(Vc.x, 1); R1v = __shfl_down(Vc.y, 1);
        if (isR) { float2 s = *(const float2*)&lds[(16 + cr) * LDSW + 256]; R0v = s.x; R1v = s.y; }
        if (isL) { float2 s = *(const float2*)&lds[(16 + cr) * LDSW + 254]; L2v = s.x; L3v = s.y; }
        #pragma unroll
        for (int e = 0; e < 4; ++e) {
            const float fm2 = e == 0 ? L2v : e == 1 ? L3v : elem(Vc, e - 2);
            const float fm1 = e == 0 ? L3v : elem(Vc, e - 1);
            const float fc  = elem(Vc, e);
            const float fp1 = e == 3 ? R0v : elem(Vc, e + 1);
            const float fp2 = e == 2 ? R0v : e == 3 ? R1v : elem(Vc, e + 2);
            float gx, gxx, gz, gzz;
            grad12(fm2, fm1, fc, fp1, fp2, x0 + e, WW, invdx, gx, gxx);
            grad12(elem(Zm2, e), elem(Zm1, e), fc, elem(Zp1, e), elem(Zp2, e), z, HH, invdz, gz, gzz);
            float gt;
            if (t == 0)            gt = (elem(Vn, e) - fc) * invdt;
            else if (t == TS - 1)  gt = (fc - elem(Vp, e)) * invdt;
            else                   gt = (elem(Vn, e) - elem(Vp, e)) * (0.5f * invdt);
            const float uxc = elem(Uc, e);
            float zm = gt + uxc * gx + fc * gz + dPdz[e] - NU * (gxx + gzz) - elem(Tc, e);
            acc += zm * zm;
            float dv = dUdxS[e] + gz;
            acc += dv * dv;
        }

        __syncthreads();   // protect LDS until all waves done reading

        Tp = Tc; Tc = Tn;
        Up = Uc; Uc = Un;
        Vp = Vc; Vc = Vn;
    }

    // block reduction: wave shfl -> LDS -> one double atomic per block
    #pragma unroll
    for (int off = 32; off; off >>= 1) acc += __shfl_down(acc, off, 64);
    __shared__ float wsum[8];
    if (lane == 0) wsum[w] = acc;
    __syncthreads();
    if (threadIdx.x == 0) {
        float s = wsum[0] + wsum[1] + wsum[2] + wsum[3]
                + wsum[4] + wsum[5] + wsum[6] + wsum[7];
        atomicAdd(dacc, (double)s);
    }
}

__global__ void rbc_finalize(const double* __restrict__ dacc, float* __restrict__ out) {
    const double N = (double)NB * TS * HH * WW;   // 12,582,912
    out[0] = (float)(dacc[0] / N);
}

extern "C" void kernel_launch(void* const* d_in, const int* in_sizes, int n_in,
                              void* d_out, int out_size, void* d_ws, size_t ws_size,
                              hipStream_t stream) {
    const float* pred = (const float*)d_in[0];
    double* dacc = (double*)d_ws;
    hipMemsetAsync(dacc, 0, sizeof(double), stream);

    const int nblocks = NB * NCH * NZB;   // 512 blocks x 512 threads = 2 blocks/CU
    rbc_loss_kernel<<<nblocks, 512, 0, stream>>>(pred, dacc);
    rbc_finalize<<<1, 1, 0, stream>>>(dacc, (float*)d_out);
}

// Round 9
// 89.581 us; speedup vs baseline: 1.5116x; 1.5116x over previous
//
#include <hip/hip_runtime.h>

#define WW 512
#define HH 256
#define TS 48
#define NB 2
#define TCH 12               // t-steps per block
#define NCH (TS / TCH)       // 4 chunks
#define KAPPA 0.01f
#define NU 0.01f

#define ROW(zz) (min(max((zz), 0), HH - 1) * WW)
#define LD4(p) (*reinterpret_cast<const float4*>(p))
#define LD2(p) (*reinterpret_cast<const float2*>(p))

__device__ __forceinline__ float elem(const float4 v, int e) {
    return e == 0 ? v.x : e == 1 ? v.y : e == 2 ? v.z : v.w;
}
__device__ __forceinline__ float4 f4add(const float4 a, const float4 b) {
    return make_float4(a.x + b.x, a.y + b.y, a.z + b.z, a.w + b.w);
}

// jnp.gradient first+second (gradient-of-gradient) along one axis, index i of n.
__device__ __forceinline__ void grad12(float fm2, float fm1, float fc, float fp1, float fp2,
                                       int i, int n, float invh, float& g, float& gg) {
    const float half = 0.5f * invh;
    if (i == 0) {
        g = (fp1 - fc) * invh;
        float g1 = (fp2 - fc) * half;
        gg = (g1 - g) * invh;
    } else if (i == n - 1) {
        g = (fc - fm1) * invh;
        float gm = (fc - fm2) * half;
        gg = (g - gm) * invh;
    } else {
        g = (fp1 - fm1) * half;
        float gim = (i == 1)     ? (fc - fm1) * invh : (fc - fm2) * half;
        float gip = (i == n - 2) ? (fp1 - fc) * invh : (fp2 - fc) * half;
        gg = (gip - gim) * half;
    }
}

__device__ __forceinline__ float grad1(float fm1, float fc, float fp1, int i, int n, float invh) {
    if (i == 0)     return (fp1 - fc) * invh;
    if (i == n - 1) return (fc - fm1) * invh;
    return (fp1 - fm1) * (0.5f * invh);
}

__global__ __launch_bounds__(256) void rbc_loss_kernel(const float* __restrict__ pred,
                                                       double* __restrict__ dacc) {
    const int sT = HH * WW;          // 131072
    const int sC = TS * sT;
    const int sB = 5 * sC;

    // XCD-chunked swizzle: 1024 blocks, 128 per XCD -> one XCD sweeps all z of
    // one (b, tc): z-neighbor row reuse stays inside its L2/L3 slice.
    const int bi = blockIdx.x;
    const int n  = (bi & 7) * (gridDim.x >> 3) + (bi >> 3);

    const int zp = n & 127;               // n = ((b*NCH + tc)*128 + zp)
    const int tc = (n >> 7) & (NCH - 1);
    const int b  = n >> 9;
    const int t0 = tc * TCH;

    const int lane = threadIdx.x & 63, w = threadIdx.x >> 6;
    const int z  = (zp << 1) + (w >> 1);          // waves 0,1 -> row A; 2,3 -> row B
    const int x0 = ((w & 1) << 8) + (lane << 2);  // quad base within row half

    const float invdt = TS / 10.0f;
    const float invdx = (float)(WW / 6.283185307179586);
    const float invdz = HH / 2.0f;

    const float* __restrict__ pT = pred + (size_t)b * sB + 0 * (size_t)sC;
    const float* __restrict__ pU = pred + (size_t)b * sB + 1 * (size_t)sC;
    const float* __restrict__ pV = pred + (size_t)b * sB + 2 * (size_t)sC;
    const float* __restrict__ q3 = pred + (size_t)b * sB + 3 * (size_t)sC;
    const float* __restrict__ q4 = pred + (size_t)b * sB + 4 * (size_t)sC;

    const int rowB = z * WW;
    const int rC   = rowB + x0;
    const int rzm2 = ROW(z - 2) + x0, rzm1 = ROW(z - 1) + x0;
    const int rzp1 = ROW(z + 1) + x0, rzp2 = ROW(z + 2) + x0;

    // seam between the two half-row waves (x=255|256 of each row)
    const bool isR = (lane == 63) && !(w & 1);   // quad 252-255, needs 256,257
    const bool isL = (lane == 0)  &&  (w & 1);   // quad 256-259, needs 254,255
    const int rSm  = rowB + (isR ? 256 : 254);   // float2 covers both needed x
    const int rSmP = rowB + (isR ? 256 : 255);

    // t-ring warm-up: planes t0-1 (clamped), t0, t0+1 (clamped)
    const int tp0 = max(t0 - 1, 0);
    const int tn0 = min(t0 + 1, TS - 1);
    float4 Tp = LD4(pT + (size_t)tp0 * sT + rC);
    float4 Up = LD4(pU + (size_t)tp0 * sT + rC);
    float4 Vp = LD4(pV + (size_t)tp0 * sT + rC);
    float4 Tc = LD4(pT + (size_t)t0 * sT + rC);
    float4 Uc = LD4(pU + (size_t)t0 * sT + rC);
    float4 Vc = LD4(pV + (size_t)t0 * sT + rC);
    float4 Tn = LD4(pT + (size_t)tn0 * sT + rC);
    float4 Un = LD4(pU + (size_t)tn0 * sT + rC);
    float4 Vn = LD4(pV + (size_t)tn0 * sT + rC);

    float acc = 0.f;

    #pragma unroll 1
    for (int t = t0; t < t0 + TCH; ++t) {
        const size_t o  = (size_t)t * sT;
        const size_t of = (size_t)min(t + 2, TS - 1) * sT;   // next iter's t+1

        // ---- issue order = consumption order ----
        // P rows (consumed first)
        float4 A3m = LD4(q3 + o + rzm1), A4m = LD4(q4 + o + rzm1);
        float4 A3c = LD4(q3 + o + rC),   A4c = LD4(q4 + o + rC);
        float4 A3p = LD4(q3 + o + rzp1), A4p = LD4(q4 + o + rzp1);
        // z-stencil rows: T then U then V (consumed in that order)
        float4 Tm2 = LD4(pT + o + rzm2), Tm1 = LD4(pT + o + rzm1);
        float4 Tp1 = LD4(pT + o + rzp1), Tp2 = LD4(pT + o + rzp2);
        float4 Um2 = LD4(pU + o + rzm2), Um1 = LD4(pU + o + rzm1);
        float4 Up1 = LD4(pU + o + rzp1), Up2 = LD4(pU + o + rzp2);
        float4 Vm2 = LD4(pV + o + rzm2), Vm1 = LD4(pV + o + rzm1);
        float4 Vp1 = LD4(pV + o + rzp1), Vp2 = LD4(pV + o + rzp2);
        // seam fixups (2 lanes/wave, exec-masked)
        float2 Tse = make_float2(0.f, 0.f), Use = Tse, Vse = Tse; float Pse = 0.f;
        if (isR | isL) {
            Tse = LD2(pT + o + rSm); Use = LD2(pU + o + rSm); Vse = LD2(pV + o + rSm);
            Pse = q3[o + rSmP] + q4[o + rSmP];
        }
        // t+2 center prefetch LAST: consumed only in NEXT iteration (ring shift),
        // so it never gates this iteration's vmcnt waits and gets a full
        // compute phase (~800 VALU cycles) to cover HBM/L3 latency.
        float4 Tf = LD4(pT + of + rC);
        float4 Uf = LD4(pU + of + rC);
        float4 Vf = LD4(pV + of + rC);

        float4 Pm1 = f4add(A3m, A4m), Pc = f4add(A3c, A4c), Pp1 = f4add(A3p, A4p);

        // x-neighbors via intra-wave shuffles of center quads (ring regs, no wait)
        float Tl2 = __shfl_up(Tc.z, 1),   Tl3 = __shfl_up(Tc.w, 1);
        float Tr0 = __shfl_down(Tc.x, 1), Tr1 = __shfl_down(Tc.y, 1);
        float Ul2 = __shfl_up(Uc.z, 1),   Ul3 = __shfl_up(Uc.w, 1);
        float Ur0 = __shfl_down(Uc.x, 1), Ur1 = __shfl_down(Uc.y, 1);
        float Vl2 = __shfl_up(Vc.z, 1),   Vl3 = __shfl_up(Vc.w, 1);
        float Vr0 = __shfl_down(Vc.x, 1), Vr1 = __shfl_down(Vc.y, 1);
        float Pl3 = __shfl_up(Pc.w, 1),   Pr0 = __shfl_down(Pc.x, 1);

        if (isR) { Tr0 = Tse.x; Tr1 = Tse.y; Ur0 = Use.x; Ur1 = Use.y;
                   Vr0 = Vse.x; Vr1 = Vse.y; Pr0 = Pse; }
        if (isL) { Tl2 = Tse.x; Tl3 = Tse.y; Ul2 = Use.x; Ul3 = Use.y;
                   Vl2 = Vse.x; Vl3 = Vse.y; Pl3 = Pse; }

        #pragma unroll
        for (int e = 0; e < 4; ++e) {
            const int i = x0 + e;
            const float txm2 = e == 0 ? Tl2 : e == 1 ? Tl3 : elem(Tc, e - 2);
            const float txm1 = e == 0 ? Tl3 : elem(Tc, e - 1);
            const float txc  = elem(Tc, e);
            const float txp1 = e == 3 ? Tr0 : elem(Tc, e + 1);
            const float txp2 = e == 2 ? Tr0 : e == 3 ? Tr1 : elem(Tc, e + 2);
            const float uxm2 = e == 0 ? Ul2 : e == 1 ? Ul3 : elem(Uc, e - 2);
            const float uxm1 = e == 0 ? Ul3 : elem(Uc, e - 1);
            const float uxc  = elem(Uc, e);
            const float uxp1 = e == 3 ? Ur0 : elem(Uc, e + 1);
            const float uxp2 = e == 2 ? Ur0 : e == 3 ? Ur1 : elem(Uc, e + 2);
            const float vxm2 = e == 0 ? Vl2 : e == 1 ? Vl3 : elem(Vc, e - 2);
            const float vxm1 = e == 0 ? Vl3 : elem(Vc, e - 1);
            const float vxc  = elem(Vc, e);
            const float vxp1 = e == 3 ? Vr0 : elem(Vc, e + 1);
            const float vxp2 = e == 2 ? Vr0 : e == 3 ? Vr1 : elem(Vc, e + 2);
            const float pxm1 = e == 0 ? Pl3 : elem(Pc, e - 1);
            const float pxc  = elem(Pc, e);
            const float pxp1 = e == 3 ? Pr0 : elem(Pc, e + 1);

            // x-grads first (ring regs only), then P, then z-stencil, then dt
            float dTdx, dTdxx, dTdz, dTdzz;
            grad12(txm2, txm1, txc, txp1, txp2, i, WW, invdx, dTdx, dTdxx);
            float dUdx, dUdxx, dUdz, dUdzz;
            grad12(uxm2, uxm1, uxc, uxp1, uxp2, i, WW, invdx, dUdx, dUdxx);
            float dVdx, dVdxx, dVdz, dVdzz;
            grad12(vxm2, vxm1, vxc, vxp1, vxp2, i, WW, invdx, dVdx, dVdxx);

            float dPdx = grad1(pxm1, pxc, pxp1, i, WW, invdx);
            float dPdz = grad1(elem(Pm1, e), pxc, elem(Pp1, e), z, HH, invdz);

            grad12(elem(Tm2, e), elem(Tm1, e), txc, elem(Tp1, e), elem(Tp2, e), z, HH, invdz, dTdz, dTdzz);
            grad12(elem(Um2, e), elem(Um1, e), uxc, elem(Up1, e), elem(Up2, e), z, HH, invdz, dUdz, dUdzz);
            grad12(elem(Vm2, e), elem(Vm1, e), vxc, elem(Vp1, e), elem(Vp2, e), z, HH, invdz, dVdz, dVdzz);

            float dTdt, dUdt, dVdt;   // t is loop-uniform; Tn/Tp already in regs
            if (t == 0) {
                dTdt = (elem(Tn, e) - txc) * invdt;
                dUdt = (elem(Un, e) - uxc) * invdt;
                dVdt = (elem(Vn, e) - vxc) * invdt;
            } else if (t == TS - 1) {
                dTdt = (txc - elem(Tp, e)) * invdt;
                dUdt = (uxc - elem(Up, e)) * invdt;
                dVdt = (vxc - elem(Vp, e)) * invdt;
            } else {
                dTdt = (elem(Tn, e) - elem(Tp, e)) * (0.5f * invdt);
                dUdt = (elem(Un, e) - elem(Up, e)) * (0.5f * invdt);
                dVdt = (elem(Vn, e) - elem(Vp, e)) * (0.5f * invdt);
            }

            float dv = dUdx + dVdz;
            float te = dTdt + uxc * dTdx + vxc * dTdz - KAPPA * (dTdxx + dTdzz);
            float xm = dUdt + uxc * dUdx + vxc * dUdz + dPdx - NU * (dUdxx + dUdzz);
            float zm = dVdt + uxc * dVdx + vxc * dVdz + dPdz - NU * (dVdxx + dVdzz) - txc;

            acc += dv * dv + te * te + xm * xm + zm * zm;
        }

        // ring shift: Tf (t+2) becomes next iteration's Tn (its t+1)
        Tp = Tc; Tc = Tn; Tn = Tf;
        Up = Uc; Uc = Un; Un = Uf;
        Vp = Vc; Vc = Vn; Vn = Vf;
    }

    // block reduction: wave shfl -> LDS -> one double atomic per block
    #pragma unroll
    for (int off = 32; off; off >>= 1) acc += __shfl_down(acc, off, 64);
    __shared__ float wsum[4];
    if (lane == 0) wsum[w] = acc;
    __syncthreads();
    if (threadIdx.x == 0) {
        atomicAdd(dacc, (double)(wsum[0] + wsum[1] + wsum[2] + wsum[3]));
    }
}

__global__ void rbc_finalize(const double* __restrict__ dacc, float* __restrict__ out) {
    const double N = (double)NB * TS * HH * WW;   // 12,582,912
    out[0] = (float)(dacc[0] / N);
}

extern "C" void kernel_launch(void* const* d_in, const int* in_sizes, int n_in,
                              void* d_out, int out_size, void* d_ws, size_t ws_size,
                              hipStream_t stream) {
    const float* pred = (const float*)d_in[0];
    double* dacc = (double*)d_ws;
    hipMemsetAsync(dacc, 0, sizeof(double), stream);

    const int nblocks = NB * NCH * (HH / 2);   // 1024 blocks x 256 threads
    rbc_loss_kernel<<<nblocks, 256, 0, stream>>>(pred, dacc);
    rbc_finalize<<<1, 1, 0, stream>>>(dacc, (float*)d_out);
}

// Round 10
// 87.359 us; speedup vs baseline: 1.5500x; 1.0254x over previous
//
#include <hip/hip_runtime.h>

#define WW 512
#define HH 256
#define TS 48
#define NB 2
#define TCH 24               // t-steps per block (2 chunks)
#define NCH (TS / TCH)       // 2
#define KAPPA 0.01f
#define NU 0.01f

#define ROW(zz) (min(max((zz), 0), HH - 1) * WW)
#define LD4(p) (*reinterpret_cast<const float4*>(p))
#define LD2(p) (*reinterpret_cast<const float2*>(p))

__device__ __forceinline__ float elem(const float4 v, int e) {
    return e == 0 ? v.x : e == 1 ? v.y : e == 2 ? v.z : v.w;
}
__device__ __forceinline__ float4 f4add(const float4 a, const float4 b) {
    return make_float4(a.x + b.x, a.y + b.y, a.z + b.z, a.w + b.w);
}

// jnp.gradient first+second (gradient-of-gradient) along one axis, index i of n.
__device__ __forceinline__ void grad12(float fm2, float fm1, float fc, float fp1, float fp2,
                                       int i, int n, float invh, float& g, float& gg) {
    const float half = 0.5f * invh;
    if (i == 0) {
        g = (fp1 - fc) * invh;
        float g1 = (fp2 - fc) * half;
        gg = (g1 - g) * invh;
    } else if (i == n - 1) {
        g = (fc - fm1) * invh;
        float gm = (fc - fm2) * half;
        gg = (g - gm) * invh;
    } else {
        g = (fp1 - fm1) * half;
        float gim = (i == 1)     ? (fc - fm1) * invh : (fc - fm2) * half;
        float gip = (i == n - 2) ? (fp1 - fc) * invh : (fp2 - fc) * half;
        gg = (gip - gim) * half;
    }
}

__device__ __forceinline__ float grad1(float fm1, float fc, float fp1, int i, int n, float invh) {
    if (i == 0)     return (fp1 - fc) * invh;
    if (i == n - 1) return (fc - fm1) * invh;
    return (fp1 - fm1) * (0.5f * invh);
}

__global__ __launch_bounds__(256) void rbc_loss_kernel(const float* __restrict__ pred,
                                                       double* __restrict__ dacc) {
    const int sT = HH * WW;          // 131072
    const int sC = TS * sT;
    const int sB = 5 * sC;

    // XCD partitioning: 512 blocks; hardware round-robins XCD = bi & 7.
    // Group g = bi&7 encodes (b, tc, xh) -> each XCD owns ONE group:
    // 256 z-rows x 256 x-half at a single t-step = 5ch x 256KB = 1.3 MB,
    // which fits the 4 MB per-XCD L2 (z-stencil/P rows become L2 hits).
    const int bi = blockIdx.x;
    const int g  = bi & 7;
    const int zb = bi >> 3;              // 0..63
    const int xh = g & 1;
    const int tc = (g >> 1) & 1;
    const int b  = g >> 2;
    const int t0 = tc * TCH;

    const int lane = threadIdx.x & 63, w = threadIdx.x >> 6;
    const int z  = (zb << 2) + w;                 // wave = one z-row
    const int x0 = (xh << 8) + (lane << 2);       // quad base within x-half

    const float invdt = TS / 10.0f;
    const float invdx = (float)(WW / 6.283185307179586);
    const float invdz = HH / 2.0f;

    const float* __restrict__ pT = pred + (size_t)b * sB + 0 * (size_t)sC;
    const float* __restrict__ pU = pred + (size_t)b * sB + 1 * (size_t)sC;
    const float* __restrict__ pV = pred + (size_t)b * sB + 2 * (size_t)sC;
    const float* __restrict__ q3 = pred + (size_t)b * sB + 3 * (size_t)sC;
    const float* __restrict__ q4 = pred + (size_t)b * sB + 4 * (size_t)sC;

    const int rowB = z * WW;
    const int rC   = rowB + x0;
    const int rzm2 = ROW(z - 2) + x0, rzm1 = ROW(z - 1) + x0;
    const int rzp1 = ROW(z + 1) + x0, rzp2 = ROW(z + 2) + x0;

    // seam at the x-half boundary (x=255|256)
    const bool isR = (lane == 63) && (xh == 0);   // quad 252-255, needs 256,257
    const bool isL = (lane == 0)  && (xh == 1);   // quad 256-259, needs 254,255
    const int rSm  = rowB + (isR ? 256 : 254);
    const int rSmP = rowB + (isR ? 256 : 255);

    // t-ring warm-up: planes t0-1 (clamped), t0, t0+1
    const int tp0 = max(t0 - 1, 0);
    const int tn0 = min(t0 + 1, TS - 1);
    float4 Tp = LD4(pT + (size_t)tp0 * sT + rC);
    float4 Up = LD4(pU + (size_t)tp0 * sT + rC);
    float4 Vp = LD4(pV + (size_t)tp0 * sT + rC);
    float4 Tc = LD4(pT + (size_t)t0 * sT + rC);
    float4 Uc = LD4(pU + (size_t)t0 * sT + rC);
    float4 Vc = LD4(pV + (size_t)t0 * sT + rC);
    float4 Tn = LD4(pT + (size_t)tn0 * sT + rC);
    float4 Un = LD4(pU + (size_t)tn0 * sT + rC);
    float4 Vn = LD4(pV + (size_t)tn0 * sT + rC);

    float acc = 0.f;

    #pragma unroll 1
    for (int t = t0; t < t0 + TCH; ++t) {
        const size_t o  = (size_t)t * sT;
        const size_t of = (size_t)min(t + 2, TS - 1) * sT;   // next iter's t+1

        // ---- issue order = consumption order ----
        // P rows (consumed first)
        float4 A3m = LD4(q3 + o + rzm1), A4m = LD4(q4 + o + rzm1);
        float4 A3c = LD4(q3 + o + rC),   A4c = LD4(q4 + o + rC);
        float4 A3p = LD4(q3 + o + rzp1), A4p = LD4(q4 + o + rzp1);
        // z-stencil rows: T then U then V (consumed in that order)
        float4 Tm2 = LD4(pT + o + rzm2), Tm1 = LD4(pT + o + rzm1);
        float4 Tp1 = LD4(pT + o + rzp1), Tp2 = LD4(pT + o + rzp2);
        float4 Um2 = LD4(pU + o + rzm2), Um1 = LD4(pU + o + rzm1);
        float4 Up1 = LD4(pU + o + rzp1), Up2 = LD4(pU + o + rzp2);
        float4 Vm2 = LD4(pV + o + rzm2), Vm1 = LD4(pV + o + rzm1);
        float4 Vp1 = LD4(pV + o + rzp1), Vp2 = LD4(pV + o + rzp2);
        // seam fixups (2 lanes/wave, exec-masked)
        float2 Tse = make_float2(0.f, 0.f), Use = Tse, Vse = Tse; float Pse = 0.f;
        if (isR | isL) {
            Tse = LD2(pT + o + rSm); Use = LD2(pU + o + rSm); Vse = LD2(pV + o + rSm);
            Pse = q3[o + rSmP] + q4[o + rSmP];
        }
        // t+2 center prefetch LAST: consumed only next iteration
        float4 Tf = LD4(pT + of + rC);
        float4 Uf = LD4(pU + of + rC);
        float4 Vf = LD4(pV + of + rC);

        float4 Pm1 = f4add(A3m, A4m), Pc = f4add(A3c, A4c), Pp1 = f4add(A3p, A4p);

        // x-neighbors via intra-wave shuffles of center quads (ring regs, no wait)
        float Tl2 = __shfl_up(Tc.z, 1),   Tl3 = __shfl_up(Tc.w, 1);
        float Tr0 = __shfl_down(Tc.x, 1), Tr1 = __shfl_down(Tc.y, 1);
        float Ul2 = __shfl_up(Uc.z, 1),   Ul3 = __shfl_up(Uc.w, 1);
        float Ur0 = __shfl_down(Uc.x, 1), Ur1 = __shfl_down(Uc.y, 1);
        float Vl2 = __shfl_up(Vc.z, 1),   Vl3 = __shfl_up(Vc.w, 1);
        float Vr0 = __shfl_down(Vc.x, 1), Vr1 = __shfl_down(Vc.y, 1);
        float Pl3 = __shfl_up(Pc.w, 1),   Pr0 = __shfl_down(Pc.x, 1);

        if (isR) { Tr0 = Tse.x; Tr1 = Tse.y; Ur0 = Use.x; Ur1 = Use.y;
                   Vr0 = Vse.x; Vr1 = Vse.y; Pr0 = Pse; }
        if (isL) { Tl2 = Tse.x; Tl3 = Tse.y; Ul2 = Use.x; Ul3 = Use.y;
                   Vl2 = Vse.x; Vl3 = Vse.y; Pl3 = Pse; }

        #pragma unroll
        for (int e = 0; e < 4; ++e) {
            const int i = x0 + e;
            const float txm2 = e == 0 ? Tl2 : e == 1 ? Tl3 : elem(Tc, e - 2);
            const float txm1 = e == 0 ? Tl3 : elem(Tc, e - 1);
            const float txc  = elem(Tc, e);
            const float txp1 = e == 3 ? Tr0 : elem(Tc, e + 1);
            const float txp2 = e == 2 ? Tr0 : e == 3 ? Tr1 : elem(Tc, e + 2);
            const float uxm2 = e == 0 ? Ul2 : e == 1 ? Ul3 : elem(Uc, e - 2);
            const float uxm1 = e == 0 ? Ul3 : elem(Uc, e - 1);
            const float uxc  = elem(Uc, e);
            const float uxp1 = e == 3 ? Ur0 : elem(Uc, e + 1);
            const float uxp2 = e == 2 ? Ur0 : e == 3 ? Ur1 : elem(Uc, e + 2);
            const float vxm2 = e == 0 ? Vl2 : e == 1 ? Vl3 : elem(Vc, e - 2);
            const float vxm1 = e == 0 ? Vl3 : elem(Vc, e - 1);
            const float vxc  = elem(Vc, e);
            const float vxp1 = e == 3 ? Vr0 : elem(Vc, e + 1);
            const float vxp2 = e == 2 ? Vr0 : e == 3 ? Vr1 : elem(Vc, e + 2);
            const float pxm1 = e == 0 ? Pl3 : elem(Pc, e - 1);
            const float pxc  = elem(Pc, e);
            const float pxp1 = e == 3 ? Pr0 : elem(Pc, e + 1);

            float dTdx, dTdxx, dTdz, dTdzz;
            grad12(txm2, txm1, txc, txp1, txp2, i, WW, invdx, dTdx, dTdxx);
            float dUdx, dUdxx, dUdz, dUdzz;
            grad12(uxm2, uxm1, uxc, uxp1, uxp2, i, WW, invdx, dUdx, dUdxx);
            float dVdx, dVdxx, dVdz, dVdzz;
            grad12(vxm2, vxm1, vxc, vxp1, vxp2, i, WW, invdx, dVdx, dVdxx);

            float dPdx = grad1(pxm1, pxc, pxp1, i, WW, invdx);
            float dPdz = grad1(elem(Pm1, e), pxc, elem(Pp1, e), z, HH, invdz);

            grad12(elem(Tm2, e), elem(Tm1, e), txc, elem(Tp1, e), elem(Tp2, e), z, HH, invdz, dTdz, dTdzz);
            grad12(elem(Um2, e), elem(Um1, e), uxc, elem(Up1, e), elem(Up2, e), z, HH, invdz, dUdz, dUdzz);
            grad12(elem(Vm2, e), elem(Vm1, e), vxc, elem(Vp1, e), elem(Vp2, e), z, HH, invdz, dVdz, dVdzz);

            float dTdt, dUdt, dVdt;   // t is loop-uniform; Tn/Tp already in regs
            if (t == 0) {
                dTdt = (elem(Tn, e) - txc) * invdt;
                dUdt = (elem(Un, e) - uxc) * invdt;
                dVdt = (elem(Vn, e) - vxc) * invdt;
            } else if (t == TS - 1) {
                dTdt = (txc - elem(Tp, e)) * invdt;
                dUdt = (uxc - elem(Up, e)) * invdt;
                dVdt = (vxc - elem(Vp, e)) * invdt;
            } else {
                dTdt = (elem(Tn, e) - elem(Tp, e)) * (0.5f * invdt);
                dUdt = (elem(Un, e) - elem(Up, e)) * (0.5f * invdt);
                dVdt = (elem(Vn, e) - elem(Vp, e)) * (0.5f * invdt);
            }

            float dv = dUdx + dVdz;
            float te = dTdt + uxc * dTdx + vxc * dTdz - KAPPA * (dTdxx + dTdzz);
            float xm = dUdt + uxc * dUdx + vxc * dUdz + dPdx - NU * (dUdxx + dUdzz);
            float zm = dVdt + uxc * dVdx + vxc * dVdz + dPdz - NU * (dVdxx + dVdzz) - txc;

            acc += dv * dv + te * te + xm * xm + zm * zm;
        }

        // ring shift: Tf (t+2) becomes next iteration's Tn (its t+1)
        Tp = Tc; Tc = Tn; Tn = Tf;
        Up = Uc; Uc = Un; Un = Uf;
        Vp = Vc; Vc = Vn; Vn = Vf;
    }

    // block reduction: wave shfl -> LDS -> one double atomic per block
    #pragma unroll
    for (int off = 32; off; off >>= 1) acc += __shfl_down(acc, off, 64);
    __shared__ float wsum[4];
    if (lane == 0) wsum[w] = acc;
    __syncthreads();
    if (threadIdx.x == 0) {
        atomicAdd(dacc, (double)(wsum[0] + wsum[1] + wsum[2] + wsum[3]));
    }
}

__global__ void rbc_finalize(const double* __restrict__ dacc, float* __restrict__ out) {
    const double N = (double)NB * TS * HH * WW;   // 12,582,912
    out[0] = (float)(dacc[0] / N);
}

extern "C" void kernel_launch(void* const* d_in, const int* in_sizes, int n_in,
                              void* d_out, int out_size, void* d_ws, size_t ws_size,
                              hipStream_t stream) {
    const float* pred = (const float*)d_in[0];
    double* dacc = (double*)d_ws;
    hipMemsetAsync(dacc, 0, sizeof(double), stream);

    const int nblocks = 8 * 64;   // 512 blocks x 256 threads = 2 blocks/CU
    rbc_loss_kernel<<<nblocks, 256, 0, stream>>>(pred, dacc);
    rbc_finalize<<<1, 1, 0, stream>>>(dacc, (float*)d_out);
}